// Round 3
// baseline (483.840 us; speedup 1.0000x reference)
//
#include <hip/hip_runtime.h>

// (B,T,D,H,KD)=(8,1024,512,8,64), SIGMA=1.
// d_out: out [8*1024*512] f32, then attn_weights [64][1024][1024] f32.
// R7: flash restructured: 8 waves / 128 q-rows per block (halves K/V staging
// bytes + barriers per unit work; 42KB LDS -> 2 blocks/CU x 8 waves = 16
// waves/CU, same as R6; grid 512 = exactly 2/CU, no tail) + nontemporal
// stores for S/attn (S streams 33MB/XCD through 4MB L2, evicting the 3MB
// K/V working set -> every stage pays L3 latency).  GEMMs unchanged from R6.

typedef float  floatx4 __attribute__((ext_vector_type(4)));
typedef short  short8  __attribute__((ext_vector_type(8)));
typedef unsigned short ushort_t;

#define MFMA16(a, b, c) __builtin_amdgcn_mfma_f32_16x16x32_bf16((a), (b), (c), 0, 0, 0)

__device__ inline ushort_t f2b(float f) {  // f32 -> bf16 bits, RNE
    unsigned u = __builtin_bit_cast(unsigned, f);
    unsigned r = u + 0x7fffu + ((u >> 16) & 1u);
    return (ushort_t)(r >> 16);
}
__device__ inline ushort_t f2b_trunc(float f) {
    return (ushort_t)(__builtin_bit_cast(unsigned, f) >> 16);
}
__device__ inline float b2f(ushort_t s) {
    return __builtin_bit_cast(float, (unsigned)s << 16);
}

// Async global->LDS, 16B per lane.  LDS dest = wave-uniform base + lane*16.
__device__ inline void gl_lds16(const void* g, void* l) {
    __builtin_amdgcn_global_load_lds(
        (const __attribute__((address_space(1))) unsigned int*)g,
        (__attribute__((address_space(3))) unsigned int*)l, 16, 0, 0);
}

// ---------------------------------------------------------------------------
// Weight transpose + split via LDS tile (coalesced both sides):
// WT[n][k] = W[k][n]; hi=bf16(w), lo=bf16(w-hi).
// grid (64 tiles, 4 weights), 256 threads; tile = 64(k) x 64(n).
// ---------------------------------------------------------------------------
__global__ __launch_bounds__(256) void wt_cvt(
    const float* __restrict__ Wq, const float* __restrict__ Wk,
    const float* __restrict__ Wv, const float* __restrict__ Wo,
    ushort_t* __restrict__ qTh, ushort_t* __restrict__ qTl,
    ushort_t* __restrict__ kTh, ushort_t* __restrict__ kTl,
    ushort_t* __restrict__ vT,  ushort_t* __restrict__ oT)
{
    __shared__ float sT[64][65];
    const int tid = threadIdx.x;
    const int c = tid & 63, rq = tid >> 6;
    const int bx = blockIdx.x;
    const int k0 = (bx >> 3) * 64, n0 = (bx & 7) * 64;

    const float* W; ushort_t* H; ushort_t* L; bool wl;
    switch (blockIdx.y) {
        case 0:  W = Wq; H = qTh; L = qTl; wl = true;  break;
        case 1:  W = Wk; H = kTh; L = kTl; wl = true;  break;
        case 2:  W = Wv; H = vT;  L = vT;  wl = false; break;
        default: W = Wo; H = oT;  L = oT;  wl = false; break;
    }

#pragma unroll
    for (int i = 0; i < 16; ++i) {
        const int row = i * 4 + rq;                      // k within tile
        sT[row][c] = W[(size_t)(k0 + row) * 512 + n0 + c];
    }
    __syncthreads();
#pragma unroll
    for (int i = 0; i < 16; ++i) {
        const int nrow = i * 4 + rq;                     // n within tile
        const float f = sT[c][nrow];                     // bank-conflict-free
        const ushort_t h = f2b(f);
        const size_t o = (size_t)(n0 + nrow) * 512 + k0 + c;
        H[o] = h;
        if (wl) L[o] = f2b(f - b2f(h));
    }
}

// ---------------------------------------------------------------------------
// LDS-staged MFMA GEMM, K=512, tile 64x64, BK=32, 256 threads (4 waves,
// wave w owns rows 16w..16w+15 x all 64 cols).  grid = 1024: mt=gid>>3,
// nt=gid&7 (gid%8 = n-panel -> per-XCD B locality).
// 2-phase prefetch: double-buffered LDS, stage(it+1) issued before compute(it),
// single barrier/iter (its vmcnt(0) drain overlaps the whole compute phase).
// AT=float: A fp32 staged raw, hi/lo split after LDS read (NPASS=3 uses lo).
// AT=ushort_t: A bf16.  OUTMODE 0: f32.  1: bf16 hi+lo (+ fused row-norms ->
// normOut[z][t], the 64-col n-panel is exactly one head).  2: vhT[z][d][T].
// Chunk swizzle: LDS slot = (chunk + row) % nchunks -> conflict-free reads.
// ---------------------------------------------------------------------------
template <typename AT, int NPASS, int OUTMODE>
__global__ __launch_bounds__(256) void gemm_lds(
    const AT* __restrict__ A, const ushort_t* __restrict__ BTh,
    const ushort_t* __restrict__ BTl, float* __restrict__ outF,
    ushort_t* __restrict__ outH, ushort_t* __restrict__ outL,
    float* __restrict__ normOut)
{
    constexpr bool AF = (sizeof(AT) == 4);
    __shared__ __align__(16) float    sAf[AF ? 2 * 64 * 32 : 4];   // fp32 A dbuf
    __shared__ __align__(16) ushort_t sAb[AF ? 8 : 2 * 64 * 32];   // bf16 A dbuf
    __shared__ __align__(16) ushort_t sBh[2 * 64 * 32];
    __shared__ __align__(16) ushort_t sBl[NPASS == 3 ? 2 * 64 * 32 : 8];

    const int tid = threadIdx.x;
    const int w = tid >> 6, lane = tid & 63;
    const int l15 = lane & 15, quad = lane >> 4;
    const int gid = blockIdx.x;
    const int m0 = (gid >> 3) * 64, n0 = (gid & 7) * 64;

    auto STAGE = [&](int bi, int it) {
        const int k0 = it * 32;
        if constexpr (AF) {
            // A tile 64x32 f32 = 8KB: rows of 8 chunks, swizzled.
#pragma unroll
            for (int t = 0; t < 2; ++t) {
                const int c = (w * 2 + t) * 64 + lane;
                const int row = c >> 3, slot = c & 7, kch = (slot - row) & 7;
                gl_lds16((const float*)A + (size_t)(m0 + row) * 512 + k0 + kch * 4,
                         (char*)sAf + (size_t)bi * 8192 + (size_t)(w * 2 + t) * 1024);
            }
        } else {
            // A tile 64x32 bf16 = 4KB: rows of 4 chunks.
            const int c = w * 64 + lane;
            const int row = c >> 2, slot = c & 3, kch = (slot - row) & 3;
            gl_lds16((const ushort_t*)A + (size_t)(m0 + row) * 512 + k0 + kch * 8,
                     (char*)sAb + (size_t)bi * 4096 + (size_t)w * 1024);
        }
        {
            const int c = w * 64 + lane;
            const int row = c >> 2, slot = c & 3, kch = (slot - row) & 3;
            const size_t ge = (size_t)(n0 + row) * 512 + k0 + kch * 8;
            gl_lds16(BTh + ge, (char*)sBh + (size_t)bi * 4096 + (size_t)w * 1024);
            if (NPASS == 3)
                gl_lds16(BTl + ge, (char*)sBl + (size_t)bi * 4096 + (size_t)w * 1024);
        }
    };

    floatx4 acc[4];
#pragma unroll
    for (int i = 0; i < 4; ++i) acc[i] = (floatx4){0.f, 0.f, 0.f, 0.f};

    STAGE(0, 0);
    __syncthreads();
    int cur = 0;

    for (int it = 0; it < 16; ++it) {
        if (it + 1 < 16) STAGE(cur ^ 1, it + 1);   // prefetch, drains at barrier

        const float*    Af = sAf + (size_t)cur * (AF ? 64 * 32 : 0);
        const ushort_t* Ab = sAb + (size_t)cur * (AF ? 0 : 64 * 32);
        const ushort_t* Bh = sBh + (size_t)cur * (64 * 32);
        const ushort_t* Bl = sBl + (size_t)cur * (NPASS == 3 ? 64 * 32 : 0);

        // ---- fragments ----
        short8 ah, al;
        {
            const int row = 16 * w + l15;
            if constexpr (AF) {
                float4 f0 = *(const float4*)&Af[row * 32 + ((quad * 2 + row) & 7) * 4];
                float4 f1 = *(const float4*)&Af[row * 32 + ((quad * 2 + 1 + row) & 7) * 4];
                float fv[8] = {f0.x, f0.y, f0.z, f0.w, f1.x, f1.y, f1.z, f1.w};
#pragma unroll
                for (int j = 0; j < 8; ++j) {
                    ushort_t h = f2b(fv[j]);
                    ah[j] = (short)h;
                    if (NPASS == 3) al[j] = (short)f2b(fv[j] - b2f(h));
                }
            } else {
                ah = *(const short8*)&Ab[row * 32 + ((quad + row) & 3) * 8];
            }
        }
        short8 bh[4], bl[4];
#pragma unroll
        for (int ni = 0; ni < 4; ++ni) {
            const int row = ni * 16 + l15;
            const int off = row * 32 + ((quad + row) & 3) * 8;
            bh[ni] = *(const short8*)&Bh[off];
            if (NPASS == 3) bl[ni] = *(const short8*)&Bl[off];
        }
        // ---- MFMAs ----
#pragma unroll
        for (int ni = 0; ni < 4; ++ni) {
            acc[ni] = MFMA16(ah, bh[ni], acc[ni]);
            if (NPASS == 3) {
                acc[ni] = MFMA16(al, bh[ni], acc[ni]);
                acc[ni] = MFMA16(ah, bl[ni], acc[ni]);
            }
        }
        __syncthreads();
        cur ^= 1;
    }

    // ---- epilogue ----
#pragma unroll
    for (int ni = 0; ni < 4; ++ni) {
        const int n = n0 + ni * 16 + l15;
#pragma unroll
        for (int r = 0; r < 4; ++r) {
            const int m = m0 + 16 * w + quad * 4 + r;
            const float v = acc[ni][r];
            if (OUTMODE == 0) {
                outF[(size_t)m * 512 + n] = v;
            } else if (OUTMODE == 1) {
                ushort_t h = f2b(v);
                outH[(size_t)m * 512 + n] = h;
                outL[(size_t)m * 512 + n] = f2b(v - b2f(h));
            } else {
                const int b = m >> 10, t = m & 1023, hh = n >> 6, d = n & 63;
                outH[((size_t)(b * 8 + hh) * 64 + d) * 1024 + t] = f2b(v);
            }
        }
    }
    if (OUTMODE == 1) {
        // Fused per-head squared norms: cols n0..n0+63 = head (gid&7).
#pragma unroll
        for (int r = 0; r < 4; ++r) {
            float s2 = 0.f;
#pragma unroll
            for (int ni = 0; ni < 4; ++ni) s2 = fmaf(acc[ni][r], acc[ni][r], s2);
#pragma unroll
            for (int off = 1; off < 16; off <<= 1) s2 += __shfl_xor(s2, off);
            if (l15 == 0) {
                const int m = m0 + 16 * w + quad * 4 + r;
                normOut[(size_t)((m >> 10) * 8 + (gid & 7)) * 1024 + (m & 1023)] = s2;
            }
        }
    }
}

// ---------------------------------------------------------------------------
// Fused flash (R7): block = (z, 128 q-rows), 512 threads / 8 waves; wave w
// owns rows 16w..16w+15.  grid = 512: gid = qt*64+z so gid%8==h (XCD L2
// locality for K/V).  Per 64-col tile: stage Khi/Klo/V^T (3x8KB, 1 chunk
// per thread, swizzled) -> barrier -> QK 3-pass MFMA -> exp -> S NT-store +
// P LDS strip -> SV MFMA -> barrier.  Staged bytes + barriers per q-row are
// HALF of the 4-wave form.  LDS 42KB -> 2 blocks/CU x 8 waves = 16 waves/CU
// (same as 4-wave form); grid 512 = exactly 2/CU, no tail.
// S/attn stores nontemporal: S streams ~33MB per XCD through the 4MB L2,
// evicting the 3MB K/V working set; NT keeps K/V L2-resident.
// ---------------------------------------------------------------------------
__global__ __launch_bounds__(512, 4) void flash_rbf(
    const ushort_t* __restrict__ qh_hi, const ushort_t* __restrict__ qh_lo,
    const ushort_t* __restrict__ kh_hi, const ushort_t* __restrict__ kh_lo,
    const ushort_t* __restrict__ vhT, const float* __restrict__ q2,
    const float* __restrict__ k2, float* __restrict__ S,
    ushort_t* __restrict__ attn)
{
    __shared__ __align__(16) ushort_t sKh[64 * 64];
    __shared__ __align__(16) ushort_t sKl[64 * 64];
    __shared__ __align__(16) ushort_t sV [64 * 64];
    __shared__ __align__(16) ushort_t P  [128 * 72];

    const int tid = threadIdx.x;
    const int w = tid >> 6, lane = tid & 63;
    const int l15 = lane & 15, quad = lane >> 4;
    const int gid = blockIdx.x;
    const int z = gid & 63, qt = gid >> 6;
    const int b = z >> 3, h = z & 7;
    const int q0 = qt * 128;

    // Q fragments (registers, whole block).
    const size_t qrow = (size_t)(b * 1024 + q0 + 16 * w + l15) * 512 + h * 64 + quad * 8;
    short8 aqh[2], aql[2];
    aqh[0] = *(const short8*)(qh_hi + qrow);
    aqh[1] = *(const short8*)(qh_hi + qrow + 32);
    aql[0] = *(const short8*)(qh_lo + qrow);
    aql[1] = *(const short8*)(qh_lo + qrow + 32);

    float q2v[4];
#pragma unroll
    for (int r = 0; r < 4; ++r)
        q2v[r] = q2[(size_t)z * 1024 + q0 + 16 * w + quad * 4 + r];

    floatx4 oacc[4];
#pragma unroll
    for (int i = 0; i < 4; ++i) oacc[i] = (floatx4){0.f, 0.f, 0.f, 0.f};

    const size_t Sz = (size_t)z << 20;

    // Stage geometry: 512 chunks of 16B per 8KB tile, chunk c = tid.
    const int src = tid;
    const int srow = src >> 3, sslot = src & 7, sdch = (sslot - srow) & 7;

    for (int ct = 0; ct < 16; ++ct) {
        const int col0 = ct * 64;

        // ---- stage K hi/lo + V^T tiles (1 chunk/thread/buffer, swizzled) ----
        {
            const size_t ke = (size_t)(b * 1024 + col0 + srow) * 512 + h * 64 + sdch * 8;
            const size_t ve = ((size_t)z * 64 + srow) * 1024 + col0 + sdch * 8;
            gl_lds16(kh_hi + ke, (char*)sKh + (size_t)w * 1024);
            gl_lds16(kh_lo + ke, (char*)sKl + (size_t)w * 1024);
            gl_lds16(vhT + ve,  (char*)sV  + (size_t)w * 1024);
        }
        float k2v[4];
#pragma unroll
        for (int j = 0; j < 4; ++j)
            k2v[j] = k2[(size_t)z * 1024 + col0 + j * 16 + l15];
        __syncthreads();

        // ---- QK^T, 3-pass split ----
        floatx4 s[4];
#pragma unroll
        for (int j = 0; j < 4; ++j) {
            const int row = j * 16 + l15;
            const int base = row * 64;
            short8 kh0 = *(const short8*)&sKh[base + ((quad + row) & 7) * 8];
            short8 kh1 = *(const short8*)&sKh[base + ((quad + 4 + row) & 7) * 8];
            short8 kl0 = *(const short8*)&sKl[base + ((quad + row) & 7) * 8];
            short8 kl1 = *(const short8*)&sKl[base + ((quad + 4 + row) & 7) * 8];
            s[j] = (floatx4){0.f, 0.f, 0.f, 0.f};
            s[j] = MFMA16(aqh[0], kh0, s[j]);
            s[j] = MFMA16(aqh[1], kh1, s[j]);
            s[j] = MFMA16(aql[0], kh0, s[j]);
            s[j] = MFMA16(aql[1], kh1, s[j]);
            s[j] = MFMA16(aqh[0], kl0, s[j]);
            s[j] = MFMA16(aqh[1], kl1, s[j]);
        }

        // ---- V fragments ----
        short8 gv0[4], gv1[4];
#pragma unroll
        for (int j2 = 0; j2 < 4; ++j2) {
            const int row = j2 * 16 + l15;
            const int base = row * 64;
            gv0[j2] = *(const short8*)&sV[base + ((quad + row) & 7) * 8];
            gv1[j2] = *(const short8*)&sV[base + ((quad + 4 + row) & 7) * 8];
        }

        // ---- exp, S NT-store, P pack ----
#pragma unroll
        for (int j = 0; j < 4; ++j) {
#pragma unroll
            for (int r = 0; r < 4; ++r) {
                const float val = __expf(2.f * s[j][r] - q2v[r] - k2v[j]);
                const int row = q0 + 16 * w + quad * 4 + r;
                __builtin_nontemporal_store(
                    val, &S[Sz + (size_t)row * 1024 + col0 + j * 16 + l15]);
                P[(16 * w + quad * 4 + r) * 72 + j * 16 + l15] = f2b_trunc(val);
            }
        }

        // ---- P readback (A-layout, wave-local) + S@V ----
        short8 pf0 = *(const short8*)&P[(16 * w + l15) * 72 + quad * 8];
        short8 pf1 = *(const short8*)&P[(16 * w + l15) * 72 + 32 + quad * 8];
#pragma unroll
        for (int j2 = 0; j2 < 4; ++j2) {
            oacc[j2] = MFMA16(pf0, gv0[j2], oacc[j2]);
            oacc[j2] = MFMA16(pf1, gv1[j2], oacc[j2]);
        }
        __syncthreads();
    }

#pragma unroll
    for (int j2 = 0; j2 < 4; ++j2)
#pragma unroll
        for (int r = 0; r < 4; ++r) {
            const int row = q0 + 16 * w + quad * 4 + r;
            __builtin_nontemporal_store(
                f2b(oacc[j2][r]),
                &attn[(size_t)(b * 1024 + row) * 512 + h * 64 + j2 * 16 + l15]);
        }
}

extern "C" void kernel_launch(void* const* d_in, const int* in_sizes, int n_in,
                              void* d_out, int out_size, void* d_ws, size_t ws_size,
                              hipStream_t stream)
{
    const float* query = (const float*)d_in[0];
    const float* key   = (const float*)d_in[1];
    const float* value = (const float*)d_in[2];
    const float* Wq    = (const float*)d_in[3];
    const float* Wk    = (const float*)d_in[4];
    const float* Wv    = (const float*)d_in[5];
    const float* Wo    = (const float*)d_in[6];

    float* out  = (float*)d_out;
    float* Sout = out + (size_t)8192 * 512;

    const size_t NE = (size_t)8192 * 512;
    ushort_t* qh_hi   = (ushort_t*)d_ws;
    ushort_t* qh_lo   = qh_hi + NE;
    ushort_t* kh_hi   = qh_lo + NE;
    ushort_t* kh_lo   = kh_hi + NE;
    ushort_t* vhT     = kh_lo + NE;
    ushort_t* attn_bf = vhT + NE;
    ushort_t* WqT_hi  = attn_bf + NE;
    ushort_t* WqT_lo  = WqT_hi + 262144;
    ushort_t* WkT_hi  = WqT_lo + 262144;
    ushort_t* WkT_lo  = WkT_hi + 262144;
    ushort_t* WvT     = WkT_lo + 262144;
    ushort_t* WoT     = WvT + 262144;
    float*    q2      = (float*)(WoT + 262144);
    float*    k2      = q2 + 65536;

    wt_cvt<<<dim3(64, 4), 256, 0, stream>>>(Wq, Wk, Wv, Wo, WqT_hi, WqT_lo,
                                            WkT_hi, WkT_lo, WvT, WoT);

    gemm_lds<float, 3, 1><<<1024, 256, 0, stream>>>(
        query, WqT_hi, WqT_lo, nullptr, qh_hi, qh_lo, q2);
    gemm_lds<float, 3, 1><<<1024, 256, 0, stream>>>(
        key, WkT_hi, WkT_lo, nullptr, kh_hi, kh_lo, k2);
    gemm_lds<float, 1, 2><<<1024, 256, 0, stream>>>(
        value, WvT, nullptr, nullptr, vhT, nullptr, nullptr);

    flash_rbf<<<512, 512, 0, stream>>>(qh_hi, qh_lo, kh_hi, kh_lo,
                                       vhT, q2, k2, Sout, attn_bf);

    gemm_lds<ushort_t, 1, 0><<<1024, 256, 0, stream>>>(
        attn_bf, WoT, nullptr, out, nullptr, nullptr, nullptr);
}

// Round 5
// 471.507 us; speedup vs baseline: 1.0262x; 1.0262x over previous
//
#include <hip/hip_runtime.h>

// (B,T,D,H,KD)=(8,1024,512,8,64), SIGMA=1.
// d_out: out [8*1024*512] f32, then attn_weights [64][1024][1024] f32.
// R9: R6 structure + numerics (hi/lo 3-pass mandatory: R8 measured the
// tolerance wall at 6.9e-19; 1-pass bf16 = 1.73e-18 FAIL).  Two deltas:
// (a) hi/lo split moved out of the GEMM inner loop into an elementwise
//     act_cvt prepass (bit-identical math) -> GEMM loop is pure
//     ds_read+MFMA instead of VALU-bound (3:1 VALU:MFMA before);
// (b) S stores nontemporal (S = 268MB streaming, never re-read; keeps the
//     3MB/XCD K/V working set L2-resident).  attn stores stay normal
//     (R7 lesson: final GEMM re-reads attn 8x).

typedef float  floatx4 __attribute__((ext_vector_type(4)));
typedef short  short8  __attribute__((ext_vector_type(8)));
typedef unsigned short ushort_t;

#define MFMA16(a, b, c) __builtin_amdgcn_mfma_f32_16x16x32_bf16((a), (b), (c), 0, 0, 0)

__device__ inline ushort_t f2b(float f) {  // f32 -> bf16 bits, RNE
    unsigned u = __builtin_bit_cast(unsigned, f);
    unsigned r = u + 0x7fffu + ((u >> 16) & 1u);
    return (ushort_t)(r >> 16);
}
__device__ inline ushort_t f2b_trunc(float f) {
    return (ushort_t)(__builtin_bit_cast(unsigned, f) >> 16);
}
__device__ inline float b2f(ushort_t s) {
    return __builtin_bit_cast(float, (unsigned)s << 16);
}

// Async global->LDS, 16B per lane.  LDS dest = wave-uniform base + lane*16.
__device__ inline void gl_lds16(const void* g, void* l) {
    __builtin_amdgcn_global_load_lds(
        (const __attribute__((address_space(1))) unsigned int*)g,
        (__attribute__((address_space(3))) unsigned int*)l, 16, 0, 0);
}

// ---------------------------------------------------------------------------
// Weight transpose + split via LDS tile (coalesced both sides):
// WT[n][k] = W[k][n]; hi=bf16(w), lo=bf16(w-hi).
// ---------------------------------------------------------------------------
__global__ __launch_bounds__(256) void wt_cvt(
    const float* __restrict__ Wq, const float* __restrict__ Wk,
    const float* __restrict__ Wv, const float* __restrict__ Wo,
    ushort_t* __restrict__ qTh, ushort_t* __restrict__ qTl,
    ushort_t* __restrict__ kTh, ushort_t* __restrict__ kTl,
    ushort_t* __restrict__ vT,  ushort_t* __restrict__ oT)
{
    __shared__ float sT[64][65];
    const int tid = threadIdx.x;
    const int c = tid & 63, rq = tid >> 6;
    const int bx = blockIdx.x;
    const int k0 = (bx >> 3) * 64, n0 = (bx & 7) * 64;

    const float* W; ushort_t* H; ushort_t* L; bool wl;
    switch (blockIdx.y) {
        case 0:  W = Wq; H = qTh; L = qTl; wl = true;  break;
        case 1:  W = Wk; H = kTh; L = kTl; wl = true;  break;
        case 2:  W = Wv; H = vT;  L = vT;  wl = false; break;
        default: W = Wo; H = oT;  L = oT;  wl = false; break;
    }

#pragma unroll
    for (int i = 0; i < 16; ++i) {
        const int row = i * 4 + rq;                      // k within tile
        sT[row][c] = W[(size_t)(k0 + row) * 512 + n0 + c];
    }
    __syncthreads();
#pragma unroll
    for (int i = 0; i < 16; ++i) {
        const int nrow = i * 4 + rq;                     // n within tile
        const float f = sT[c][nrow];                     // bank-conflict-free
        const ushort_t h = f2b(f);
        const size_t o = (size_t)(n0 + nrow) * 512 + k0 + c;
        H[o] = h;
        if (wl) L[o] = f2b(f - b2f(h));
    }
}

// ---------------------------------------------------------------------------
// Activation hi/lo split (elementwise, vectorized): XH=bf16(x), XL=bf16(x-XH).
// Bit-identical to the former in-GEMM split.  grid 2048 x 256, 8 elems/thread.
// ---------------------------------------------------------------------------
template <bool LO>
__global__ __launch_bounds__(256) void act_cvt(
    const float* __restrict__ X, ushort_t* __restrict__ XH,
    ushort_t* __restrict__ XL)
{
    const size_t i = ((size_t)blockIdx.x * 256 + threadIdx.x) * 8;
    const float4 f0 = *(const float4*)(X + i);
    const float4 f1 = *(const float4*)(X + i + 4);
    const float fv[8] = {f0.x, f0.y, f0.z, f0.w, f1.x, f1.y, f1.z, f1.w};
    short8 h, l;
#pragma unroll
    for (int j = 0; j < 8; ++j) {
        const ushort_t hh = f2b(fv[j]);
        h[j] = (short)hh;
        if (LO) l[j] = (short)f2b(fv[j] - b2f(hh));
    }
    *(short8*)(XH + i) = h;
    if (LO) *(short8*)(XL + i) = l;
}

// ---------------------------------------------------------------------------
// LDS-staged MFMA GEMM, K=512, tile 64x64, BK=32, 256 threads (4 waves,
// wave w owns rows 16w..16w+15 x all 64 cols).  grid = 1024: mt=gid>>3,
// nt=gid&7 (gid%8 = n-panel -> per-XCD B locality).
// 2-phase prefetch: double-buffered LDS, stage(it+1) issued before
// compute(it), single barrier/iter.  All operands pre-split bf16.
// AMODE 1: A bf16, 1 MFMA/ni.  AMODE 3: A+B hi/lo, 3 MFMA/ni (hh, lh, hl).
// OUTMODE 0: f32.  1: bf16 hi+lo + fused row-norms -> normOut[z][t]
// (64-col n-panel = one head).  2: vhT[z][d][T].
// Chunk swizzle: LDS slot = (chunk + row) % 4 -> conflict-free reads.
// ---------------------------------------------------------------------------
template <int AMODE, int OUTMODE>
__global__ __launch_bounds__(256) void gemm_lds(
    const ushort_t* __restrict__ Ah, const ushort_t* __restrict__ Al,
    const ushort_t* __restrict__ BTh, const ushort_t* __restrict__ BTl,
    float* __restrict__ outF, ushort_t* __restrict__ outH,
    ushort_t* __restrict__ outL, float* __restrict__ normOut)
{
    constexpr bool NP3 = (AMODE == 3);
    __shared__ __align__(16) ushort_t sAh[2 * 64 * 32];
    __shared__ __align__(16) ushort_t sAl[NP3 ? 2 * 64 * 32 : 8];
    __shared__ __align__(16) ushort_t sBh[2 * 64 * 32];
    __shared__ __align__(16) ushort_t sBl[NP3 ? 2 * 64 * 32 : 8];

    const int tid = threadIdx.x;
    const int w = tid >> 6, lane = tid & 63;
    const int l15 = lane & 15, quad = lane >> 4;
    const int gid = blockIdx.x;
    const int m0 = (gid >> 3) * 64, n0 = (gid & 7) * 64;

    auto STAGE = [&](int bi, int it) {
        const int k0 = it * 32;
        const int c = w * 64 + lane;
        const int row = c >> 2, slot = c & 3, kch = (slot - row) & 3;
        const size_t ga = (size_t)(m0 + row) * 512 + k0 + kch * 8;
        const size_t ge = (size_t)(n0 + row) * 512 + k0 + kch * 8;
        const size_t dst = (size_t)bi * 4096 + (size_t)w * 1024;
        gl_lds16(Ah + ga, (char*)sAh + dst);
        gl_lds16(BTh + ge, (char*)sBh + dst);
        if (NP3) {
            gl_lds16(Al + ga, (char*)sAl + dst);
            gl_lds16(BTl + ge, (char*)sBl + dst);
        }
    };

    floatx4 acc[4];
#pragma unroll
    for (int i = 0; i < 4; ++i) acc[i] = (floatx4){0.f, 0.f, 0.f, 0.f};

    STAGE(0, 0);
    __syncthreads();
    int cur = 0;

    for (int it = 0; it < 16; ++it) {
        if (it + 1 < 16) STAGE(cur ^ 1, it + 1);   // prefetch, drains at barrier

        const ushort_t* Abh = sAh + (size_t)cur * (64 * 32);
        const ushort_t* Abl = sAl + (size_t)cur * (NP3 ? 64 * 32 : 0);
        const ushort_t* Bbh = sBh + (size_t)cur * (64 * 32);
        const ushort_t* Bbl = sBl + (size_t)cur * (NP3 ? 64 * 32 : 0);

        // ---- fragments ----
        short8 ah, al;
        {
            const int row = 16 * w + l15;
            const int off = row * 32 + ((quad + row) & 3) * 8;
            ah = *(const short8*)&Abh[off];
            if (NP3) al = *(const short8*)&Abl[off];
        }
        short8 bh[4], bl[4];
#pragma unroll
        for (int ni = 0; ni < 4; ++ni) {
            const int row = ni * 16 + l15;
            const int off = row * 32 + ((quad + row) & 3) * 8;
            bh[ni] = *(const short8*)&Bbh[off];
            if (NP3) bl[ni] = *(const short8*)&Bbl[off];
        }
        // ---- MFMAs ----
#pragma unroll
        for (int ni = 0; ni < 4; ++ni) {
            acc[ni] = MFMA16(ah, bh[ni], acc[ni]);
            if (NP3) {
                acc[ni] = MFMA16(al, bh[ni], acc[ni]);
                acc[ni] = MFMA16(ah, bl[ni], acc[ni]);
            }
        }
        __syncthreads();
        cur ^= 1;
    }

    // ---- epilogue ----
#pragma unroll
    for (int ni = 0; ni < 4; ++ni) {
        const int n = n0 + ni * 16 + l15;
#pragma unroll
        for (int r = 0; r < 4; ++r) {
            const int m = m0 + 16 * w + quad * 4 + r;
            const float v = acc[ni][r];
            if (OUTMODE == 0) {
                outF[(size_t)m * 512 + n] = v;
            } else if (OUTMODE == 1) {
                const ushort_t h = f2b(v);
                outH[(size_t)m * 512 + n] = h;
                outL[(size_t)m * 512 + n] = f2b(v - b2f(h));
            } else {
                const int b = m >> 10, t = m & 1023, hh = n >> 6, d = n & 63;
                outH[((size_t)(b * 8 + hh) * 64 + d) * 1024 + t] = f2b(v);
            }
        }
    }
    if (OUTMODE == 1) {
        // Fused per-head squared norms (f32, from acc): cols = head (gid&7).
#pragma unroll
        for (int r = 0; r < 4; ++r) {
            float s2 = 0.f;
#pragma unroll
            for (int ni = 0; ni < 4; ++ni) s2 = fmaf(acc[ni][r], acc[ni][r], s2);
#pragma unroll
            for (int off = 1; off < 16; off <<= 1) s2 += __shfl_xor(s2, off);
            if (l15 == 0) {
                const int m = m0 + 16 * w + quad * 4 + r;
                normOut[(size_t)((m >> 10) * 8 + (gid & 7)) * 1024 + (m & 1023)] = s2;
            }
        }
    }
}

// ---------------------------------------------------------------------------
// Fused flash (R6 structure): block = (z, 64 q-rows), 4 waves; gid = qt*64+z
// so gid%8==h (XCD L2 locality for K/V).  Per 64-col tile: stage Khi/Klo/V^T
// (3x8KB, swizzled) -> barrier -> QK 3-pass MFMA -> exp -> S NT-store +
// P LDS strip -> SV MFMA -> barrier.  33.8KB LDS -> 4 blocks/CU.
// S store nontemporal ONLY (attn normal: final GEMM re-reads it 8x).
// ---------------------------------------------------------------------------
__global__ __launch_bounds__(256) void flash_rbf(
    const ushort_t* __restrict__ qh_hi, const ushort_t* __restrict__ qh_lo,
    const ushort_t* __restrict__ kh_hi, const ushort_t* __restrict__ kh_lo,
    const ushort_t* __restrict__ vhT, const float* __restrict__ q2,
    const float* __restrict__ k2, float* __restrict__ S,
    ushort_t* __restrict__ attn)
{
    __shared__ __align__(16) ushort_t sKh[64 * 64];
    __shared__ __align__(16) ushort_t sKl[64 * 64];
    __shared__ __align__(16) ushort_t sV [64 * 64];
    __shared__ __align__(16) ushort_t P  [64 * 72];

    const int tid = threadIdx.x;
    const int w = tid >> 6, lane = tid & 63;
    const int l15 = lane & 15, quad = lane >> 4;
    const int gid = blockIdx.x;
    const int z = gid & 63, qt = gid >> 6;
    const int b = z >> 3, h = z & 7;
    const int q0 = qt * 64;

    // Q fragments (registers, whole block).
    const size_t qrow = (size_t)(b * 1024 + q0 + 16 * w + l15) * 512 + h * 64 + quad * 8;
    short8 aqh[2], aql[2];
    aqh[0] = *(const short8*)(qh_hi + qrow);
    aqh[1] = *(const short8*)(qh_hi + qrow + 32);
    aql[0] = *(const short8*)(qh_lo + qrow);
    aql[1] = *(const short8*)(qh_lo + qrow + 32);

    float q2v[4];
#pragma unroll
    for (int r = 0; r < 4; ++r)
        q2v[r] = q2[(size_t)z * 1024 + q0 + 16 * w + quad * 4 + r];

    floatx4 oacc[4];
#pragma unroll
    for (int i = 0; i < 4; ++i) oacc[i] = (floatx4){0.f, 0.f, 0.f, 0.f};

    const size_t Sz = (size_t)z << 20;

    for (int ct = 0; ct < 16; ++ct) {
        const int col0 = ct * 64;

        // ---- stage K hi/lo + V^T tiles (rows of 8 chunks, swizzled) ----
#pragma unroll
        for (int t = 0; t < 2; ++t) {
            const int c = (w * 2 + t) * 64 + lane;
            const int row = c >> 3, slot = c & 7, dch = (slot - row) & 7;
            const size_t ke = (size_t)(b * 1024 + col0 + row) * 512 + h * 64 + dch * 8;
            const size_t ve = ((size_t)z * 64 + row) * 1024 + col0 + dch * 8;
            gl_lds16(kh_hi + ke, (char*)sKh + (size_t)(w * 2 + t) * 1024);
            gl_lds16(kh_lo + ke, (char*)sKl + (size_t)(w * 2 + t) * 1024);
            gl_lds16(vhT + ve,  (char*)sV  + (size_t)(w * 2 + t) * 1024);
        }
        float k2v[4];
#pragma unroll
        for (int j = 0; j < 4; ++j)
            k2v[j] = k2[(size_t)z * 1024 + col0 + j * 16 + l15];
        __syncthreads();

        // ---- QK^T, 3-pass split ----
        floatx4 s[4];
#pragma unroll
        for (int j = 0; j < 4; ++j) {
            const int row = j * 16 + l15;
            const int base = row * 64;
            short8 kh0 = *(const short8*)&sKh[base + ((quad + row) & 7) * 8];
            short8 kh1 = *(const short8*)&sKh[base + ((quad + 4 + row) & 7) * 8];
            short8 kl0 = *(const short8*)&sKl[base + ((quad + row) & 7) * 8];
            short8 kl1 = *(const short8*)&sKl[base + ((quad + 4 + row) & 7) * 8];
            s[j] = (floatx4){0.f, 0.f, 0.f, 0.f};
            s[j] = MFMA16(aqh[0], kh0, s[j]);
            s[j] = MFMA16(aqh[1], kh1, s[j]);
            s[j] = MFMA16(aql[0], kh0, s[j]);
            s[j] = MFMA16(aql[1], kh1, s[j]);
            s[j] = MFMA16(aqh[0], kl0, s[j]);
            s[j] = MFMA16(aqh[1], kl1, s[j]);
        }

        // ---- V fragments ----
        short8 gv0[4], gv1[4];
#pragma unroll
        for (int j2 = 0; j2 < 4; ++j2) {
            const int row = j2 * 16 + l15;
            const int base = row * 64;
            gv0[j2] = *(const short8*)&sV[base + ((quad + row) & 7) * 8];
            gv1[j2] = *(const short8*)&sV[base + ((quad + 4 + row) & 7) * 8];
        }

        // ---- exp, S NT-store, P pack ----
#pragma unroll
        for (int j = 0; j < 4; ++j) {
#pragma unroll
            for (int r = 0; r < 4; ++r) {
                const float val = __expf(2.f * s[j][r] - q2v[r] - k2v[j]);
                const int row = q0 + 16 * w + quad * 4 + r;
                __builtin_nontemporal_store(
                    val, &S[Sz + (size_t)row * 1024 + col0 + j * 16 + l15]);
                P[(16 * w + quad * 4 + r) * 72 + j * 16 + l15] = f2b_trunc(val);
            }
        }

        // ---- P readback (A-layout, wave-local) + S@V ----
        short8 pf0 = *(const short8*)&P[(16 * w + l15) * 72 + quad * 8];
        short8 pf1 = *(const short8*)&P[(16 * w + l15) * 72 + 32 + quad * 8];
#pragma unroll
        for (int j2 = 0; j2 < 4; ++j2) {
            oacc[j2] = MFMA16(pf0, gv0[j2], oacc[j2]);
            oacc[j2] = MFMA16(pf1, gv1[j2], oacc[j2]);
        }
        __syncthreads();
    }

#pragma unroll
    for (int j2 = 0; j2 < 4; ++j2)
#pragma unroll
        for (int r = 0; r < 4; ++r) {
            const int row = q0 + 16 * w + quad * 4 + r;
            attn[(size_t)(b * 1024 + row) * 512 + h * 64 + j2 * 16 + l15] =
                f2b(oacc[j2][r]);
        }
}

extern "C" void kernel_launch(void* const* d_in, const int* in_sizes, int n_in,
                              void* d_out, int out_size, void* d_ws, size_t ws_size,
                              hipStream_t stream)
{
    const float* query = (const float*)d_in[0];
    const float* key   = (const float*)d_in[1];
    const float* value = (const float*)d_in[2];
    const float* Wq    = (const float*)d_in[3];
    const float* Wk    = (const float*)d_in[4];
    const float* Wv    = (const float*)d_in[5];
    const float* Wo    = (const float*)d_in[6];

    float* out  = (float*)d_out;
    float* Sout = out + (size_t)8192 * 512;

    const size_t NE = (size_t)8192 * 512;
    ushort_t* qh_hi   = (ushort_t*)d_ws;
    ushort_t* qh_lo   = qh_hi + NE;
    ushort_t* kh_hi   = qh_lo + NE;
    ushort_t* kh_lo   = kh_hi + NE;
    ushort_t* vhT     = kh_lo + NE;
    ushort_t* attn_bf = vhT + NE;      // doubles as aA_hi before flash runs
    ushort_t* aA_lo   = attn_bf + NE;  // extra 8MB: activation lo scratch
    ushort_t* WqT_hi  = aA_lo + NE;
    ushort_t* WqT_lo  = WqT_hi + 262144;
    ushort_t* WkT_hi  = WqT_lo + 262144;
    ushort_t* WkT_lo  = WkT_hi + 262144;
    ushort_t* WvT     = WkT_lo + 262144;
    ushort_t* WoT     = WvT + 262144;
    float*    q2      = (float*)(WoT + 262144);
    float*    k2      = q2 + 65536;

    ushort_t* aA_hi = attn_bf;  // alias: dead before flash writes attn_bf

    wt_cvt<<<dim3(64, 4), 256, 0, stream>>>(Wq, Wk, Wv, Wo, WqT_hi, WqT_lo,
                                            WkT_hi, WkT_lo, WvT, WoT);

    // q projection
    act_cvt<true><<<2048, 256, 0, stream>>>(query, aA_hi, aA_lo);
    gemm_lds<3, 1><<<1024, 256, 0, stream>>>(
        aA_hi, aA_lo, WqT_hi, WqT_lo, nullptr, qh_hi, qh_lo, q2);
    // k projection
    act_cvt<true><<<2048, 256, 0, stream>>>(key, aA_hi, aA_lo);
    gemm_lds<3, 1><<<1024, 256, 0, stream>>>(
        aA_hi, aA_lo, WkT_hi, WkT_lo, nullptr, kh_hi, kh_lo, k2);
    // v projection
    act_cvt<false><<<2048, 256, 0, stream>>>(value, aA_hi, nullptr);
    gemm_lds<1, 2><<<1024, 256, 0, stream>>>(
        aA_hi, nullptr, WvT, nullptr, nullptr, vhT, nullptr, nullptr);

    flash_rbf<<<1024, 256, 0, stream>>>(qh_hi, qh_lo, kh_hi, kh_lo,
                                        vhT, q2, k2, Sout, attn_bf);

    gemm_lds<1, 0><<<1024, 256, 0, stream>>>(
        attn_bf, nullptr, WoT, nullptr, out, nullptr, nullptr, nullptr);
}

// Round 6
// 442.195 us; speedup vs baseline: 1.0942x; 1.0663x over previous
//
#include <hip/hip_runtime.h>

// (B,T,D,H,KD)=(8,1024,512,8,64), SIGMA=1.
// d_out: out [8*1024*512] f32, then attn_weights [64][1024][1024] f32.
// R10: fp16 flash on the R6 structure.  R8 measured the precision wall:
// 1-pass bf16 = 1.73e-18 > 6.9e-19 threshold (need ~1.5 more bits); fp16
// has 3 more mantissa bits -> 1-pass fp16 QK predicted ~2-3e-19.  Range:
// S~1e-18 underflows fp16, so P is scaled by 2^60 before the f16 cast
// (exact exponent shift; S_max*2^60 ~ 25) and oacc by 2^-60 at the end.
// Consistency: q2/k2 accumulated from the f16-ROUNDED qh/kh, so the
// exponent is exactly ||q~-k~||^2 (error = storage rounding only).
// Projections keep the proven 3-pass bf16 hi/lo GEMM (R4/R6 numerics);
// flash: QK 6->2 MFMAs/tile, no sKl (LDS 33.8->25.2KB), P = RNE f16
// (was truncated bf16 -> SV also more accurate), V staged f16.

typedef float  floatx4 __attribute__((ext_vector_type(4)));
typedef short  short8  __attribute__((ext_vector_type(8)));
typedef _Float16 half8 __attribute__((ext_vector_type(8)));
typedef unsigned short ushort_t;

#define MFMA16(a, b, c)  __builtin_amdgcn_mfma_f32_16x16x32_bf16((a), (b), (c), 0, 0, 0)
#define MFMA16F(a, b, c) __builtin_amdgcn_mfma_f32_16x16x32_f16((a), (b), (c), 0, 0, 0)

#define P_SCALE   0x1p60f
#define P_ISCALE  0x1p-60f

__device__ inline ushort_t f2b(float f) {  // f32 -> bf16 bits, RNE
    unsigned u = __builtin_bit_cast(unsigned, f);
    unsigned r = u + 0x7fffu + ((u >> 16) & 1u);
    return (ushort_t)(r >> 16);
}
__device__ inline float b2f(ushort_t s) {
    return __builtin_bit_cast(float, (unsigned)s << 16);
}

// Async global->LDS, 16B per lane.  LDS dest = wave-uniform base + lane*16.
__device__ inline void gl_lds16(const void* g, void* l) {
    __builtin_amdgcn_global_load_lds(
        (const __attribute__((address_space(1))) unsigned int*)g,
        (__attribute__((address_space(3))) unsigned int*)l, 16, 0, 0);
}

// ---------------------------------------------------------------------------
// Weight transpose + split via LDS tile (coalesced both sides):
// WT[n][k] = W[k][n]; hi=bf16(w), lo=bf16(w-hi).
// ---------------------------------------------------------------------------
__global__ __launch_bounds__(256) void wt_cvt(
    const float* __restrict__ Wq, const float* __restrict__ Wk,
    const float* __restrict__ Wv, const float* __restrict__ Wo,
    ushort_t* __restrict__ qTh, ushort_t* __restrict__ qTl,
    ushort_t* __restrict__ kTh, ushort_t* __restrict__ kTl,
    ushort_t* __restrict__ vT,  ushort_t* __restrict__ oT)
{
    __shared__ float sT[64][65];
    const int tid = threadIdx.x;
    const int c = tid & 63, rq = tid >> 6;
    const int bx = blockIdx.x;
    const int k0 = (bx >> 3) * 64, n0 = (bx & 7) * 64;

    const float* W; ushort_t* H; ushort_t* L; bool wl;
    switch (blockIdx.y) {
        case 0:  W = Wq; H = qTh; L = qTl; wl = true;  break;
        case 1:  W = Wk; H = kTh; L = kTl; wl = true;  break;
        case 2:  W = Wv; H = vT;  L = vT;  wl = false; break;
        default: W = Wo; H = oT;  L = oT;  wl = false; break;
    }

#pragma unroll
    for (int i = 0; i < 16; ++i) {
        const int row = i * 4 + rq;                      // k within tile
        sT[row][c] = W[(size_t)(k0 + row) * 512 + n0 + c];
    }
    __syncthreads();
#pragma unroll
    for (int i = 0; i < 16; ++i) {
        const int nrow = i * 4 + rq;                     // n within tile
        const float f = sT[c][nrow];                     // bank-conflict-free
        const ushort_t h = f2b(f);
        const size_t o = (size_t)(n0 + nrow) * 512 + k0 + c;
        H[o] = h;
        if (wl) L[o] = f2b(f - b2f(h));
    }
}

// ---------------------------------------------------------------------------
// LDS-staged MFMA GEMM, K=512, tile 64x64, BK=32, 256 threads (4 waves,
// wave w owns rows 16w..16w+15 x all 64 cols).  grid = 1024: mt=gid>>3,
// nt=gid&7 (gid%8 = n-panel -> per-XCD B locality).
// 2-phase prefetch: double-buffered LDS, stage(it+1) issued before
// compute(it), single barrier/iter.  AT=float: A fp32 staged raw, hi/lo
// split after LDS read (NPASS=3 uses lo).  AT=ushort_t: A bf16.
// OUTMODE 0: f32.  1: f16 + fused row-norms from the ROUNDED value ->
// normOut[z][t] (64-col n-panel = one head; consistency: flash uses the
// same f16 values, so exponent = exact ||q~-k~||^2).  2: vhT[z][d][T] f16.
// Chunk swizzle: LDS slot = (chunk + row) % nchunks -> conflict-free reads.
// ---------------------------------------------------------------------------
template <typename AT, int NPASS, int OUTMODE>
__global__ __launch_bounds__(256) void gemm_lds(
    const AT* __restrict__ A, const ushort_t* __restrict__ BTh,
    const ushort_t* __restrict__ BTl, float* __restrict__ outF,
    ushort_t* __restrict__ outH, ushort_t* __restrict__ outL,
    float* __restrict__ normOut)
{
    constexpr bool AF = (sizeof(AT) == 4);
    __shared__ __align__(16) float    sAf[AF ? 2 * 64 * 32 : 4];   // fp32 A dbuf
    __shared__ __align__(16) ushort_t sAb[AF ? 8 : 2 * 64 * 32];   // bf16 A dbuf
    __shared__ __align__(16) ushort_t sBh[2 * 64 * 32];
    __shared__ __align__(16) ushort_t sBl[NPASS == 3 ? 2 * 64 * 32 : 8];

    const int tid = threadIdx.x;
    const int w = tid >> 6, lane = tid & 63;
    const int l15 = lane & 15, quad = lane >> 4;
    const int gid = blockIdx.x;
    const int m0 = (gid >> 3) * 64, n0 = (gid & 7) * 64;

    auto STAGE = [&](int bi, int it) {
        const int k0 = it * 32;
        if constexpr (AF) {
            // A tile 64x32 f32 = 8KB: rows of 8 chunks, swizzled.
#pragma unroll
            for (int t = 0; t < 2; ++t) {
                const int c = (w * 2 + t) * 64 + lane;
                const int row = c >> 3, slot = c & 7, kch = (slot - row) & 7;
                gl_lds16((const float*)A + (size_t)(m0 + row) * 512 + k0 + kch * 4,
                         (char*)sAf + (size_t)bi * 8192 + (size_t)(w * 2 + t) * 1024);
            }
        } else {
            // A tile 64x32 bf16 = 4KB: rows of 4 chunks.
            const int c = w * 64 + lane;
            const int row = c >> 2, slot = c & 3, kch = (slot - row) & 3;
            gl_lds16((const ushort_t*)A + (size_t)(m0 + row) * 512 + k0 + kch * 8,
                     (char*)sAb + (size_t)bi * 4096 + (size_t)w * 1024);
        }
        {
            const int c = w * 64 + lane;
            const int row = c >> 2, slot = c & 3, kch = (slot - row) & 3;
            const size_t ge = (size_t)(n0 + row) * 512 + k0 + kch * 8;
            gl_lds16(BTh + ge, (char*)sBh + (size_t)bi * 4096 + (size_t)w * 1024);
            if (NPASS == 3)
                gl_lds16(BTl + ge, (char*)sBl + (size_t)bi * 4096 + (size_t)w * 1024);
        }
    };

    floatx4 acc[4];
#pragma unroll
    for (int i = 0; i < 4; ++i) acc[i] = (floatx4){0.f, 0.f, 0.f, 0.f};

    STAGE(0, 0);
    __syncthreads();
    int cur = 0;

    for (int it = 0; it < 16; ++it) {
        if (it + 1 < 16) STAGE(cur ^ 1, it + 1);   // prefetch, drains at barrier

        const float*    Af = sAf + (size_t)cur * (AF ? 64 * 32 : 0);
        const ushort_t* Ab = sAb + (size_t)cur * (AF ? 0 : 64 * 32);
        const ushort_t* Bh = sBh + (size_t)cur * (64 * 32);
        const ushort_t* Bl = sBl + (size_t)cur * (NPASS == 3 ? 64 * 32 : 0);

        // ---- fragments ----
        short8 ah, al;
        {
            const int row = 16 * w + l15;
            if constexpr (AF) {
                float4 f0 = *(const float4*)&Af[row * 32 + ((quad * 2 + row) & 7) * 4];
                float4 f1 = *(const float4*)&Af[row * 32 + ((quad * 2 + 1 + row) & 7) * 4];
                float fv[8] = {f0.x, f0.y, f0.z, f0.w, f1.x, f1.y, f1.z, f1.w};
#pragma unroll
                for (int j = 0; j < 8; ++j) {
                    ushort_t h = f2b(fv[j]);
                    ah[j] = (short)h;
                    if (NPASS == 3) al[j] = (short)f2b(fv[j] - b2f(h));
                }
            } else {
                ah = *(const short8*)&Ab[row * 32 + ((quad + row) & 3) * 8];
            }
        }
        short8 bh[4], bl[4];
#pragma unroll
        for (int ni = 0; ni < 4; ++ni) {
            const int row = ni * 16 + l15;
            const int off = row * 32 + ((quad + row) & 3) * 8;
            bh[ni] = *(const short8*)&Bh[off];
            if (NPASS == 3) bl[ni] = *(const short8*)&Bl[off];
        }
        // ---- MFMAs ----
#pragma unroll
        for (int ni = 0; ni < 4; ++ni) {
            acc[ni] = MFMA16(ah, bh[ni], acc[ni]);
            if (NPASS == 3) {
                acc[ni] = MFMA16(al, bh[ni], acc[ni]);
                acc[ni] = MFMA16(ah, bl[ni], acc[ni]);
            }
        }
        __syncthreads();
        cur ^= 1;
    }

    // ---- epilogue ----
#pragma unroll
    for (int ni = 0; ni < 4; ++ni) {
        const int n = n0 + ni * 16 + l15;
#pragma unroll
        for (int r = 0; r < 4; ++r) {
            const int m = m0 + 16 * w + quad * 4 + r;
            const float v = acc[ni][r];
            if (OUTMODE == 0) {
                outF[(size_t)m * 512 + n] = v;
            } else if (OUTMODE == 1) {
                ((_Float16*)outH)[(size_t)m * 512 + n] = (_Float16)v;
            } else {
                const int b = m >> 10, t = m & 1023, hh = n >> 6, d = n & 63;
                ((_Float16*)outH)[((size_t)(b * 8 + hh) * 64 + d) * 1024 + t] =
                    (_Float16)v;
            }
        }
    }
    if (OUTMODE == 1) {
        // Fused per-head squared norms from the f16-ROUNDED values (must
        // match what flash reads for exact ||q~-k~||^2 expansion).
#pragma unroll
        for (int r = 0; r < 4; ++r) {
            float s2 = 0.f;
#pragma unroll
            for (int ni = 0; ni < 4; ++ni) {
                const float rv = (float)(_Float16)acc[ni][r];
                s2 = fmaf(rv, rv, s2);
            }
#pragma unroll
            for (int off = 1; off < 16; off <<= 1) s2 += __shfl_xor(s2, off);
            if (l15 == 0) {
                const int m = m0 + 16 * w + quad * 4 + r;
                normOut[(size_t)((m >> 10) * 8 + (gid & 7)) * 1024 + (m & 1023)] = s2;
            }
        }
    }
}

// ---------------------------------------------------------------------------
// Fused flash (R6 structure, fp16): block = (z, 64 q-rows), 4 waves;
// gid = qt*64+z so gid%8==h (XCD L2 locality for K/V).  Per 64-col tile:
// stage K/V^T f16 (2x8KB, swizzled) -> barrier -> QK 1-pass f16 MFMA ->
// exp -> S store + P strip (f16, x2^60) -> SV f16 MFMA -> barrier.
// 25.2KB LDS -> 4+ blocks/CU.
// ---------------------------------------------------------------------------
__global__ __launch_bounds__(256) void flash_rbf(
    const ushort_t* __restrict__ qh, const ushort_t* __restrict__ kh,
    const ushort_t* __restrict__ vhT, const float* __restrict__ q2,
    const float* __restrict__ k2, float* __restrict__ S,
    ushort_t* __restrict__ attn)
{
    __shared__ __align__(16) ushort_t sK[64 * 64];
    __shared__ __align__(16) ushort_t sV[64 * 64];
    __shared__ __align__(16) ushort_t P [64 * 72];

    const int tid = threadIdx.x;
    const int w = tid >> 6, lane = tid & 63;
    const int l15 = lane & 15, quad = lane >> 4;
    const int gid = blockIdx.x;
    const int z = gid & 63, qt = gid >> 6;
    const int b = z >> 3, h = z & 7;
    const int q0 = qt * 64;

    // Q fragments (f16 registers, whole block).
    const size_t qrow = (size_t)(b * 1024 + q0 + 16 * w + l15) * 512 + h * 64 + quad * 8;
    half8 aq0 = *(const half8*)((const _Float16*)qh + qrow);
    half8 aq1 = *(const half8*)((const _Float16*)qh + qrow + 32);

    float q2v[4];
#pragma unroll
    for (int r = 0; r < 4; ++r)
        q2v[r] = q2[(size_t)z * 1024 + q0 + 16 * w + quad * 4 + r];

    floatx4 oacc[4];
#pragma unroll
    for (int i = 0; i < 4; ++i) oacc[i] = (floatx4){0.f, 0.f, 0.f, 0.f};

    const size_t Sz = (size_t)z << 20;

    for (int ct = 0; ct < 16; ++ct) {
        const int col0 = ct * 64;

        // ---- stage K + V^T f16 tiles (rows of 8 chunks, swizzled) ----
#pragma unroll
        for (int t = 0; t < 2; ++t) {
            const int c = (w * 2 + t) * 64 + lane;
            const int row = c >> 3, slot = c & 7, dch = (slot - row) & 7;
            const size_t ke = (size_t)(b * 1024 + col0 + row) * 512 + h * 64 + dch * 8;
            const size_t ve = ((size_t)z * 64 + row) * 1024 + col0 + dch * 8;
            gl_lds16(kh + ke,  (char*)sK + (size_t)(w * 2 + t) * 1024);
            gl_lds16(vhT + ve, (char*)sV + (size_t)(w * 2 + t) * 1024);
        }
        float k2v[4];
#pragma unroll
        for (int j = 0; j < 4; ++j)
            k2v[j] = k2[(size_t)z * 1024 + col0 + j * 16 + l15];
        __syncthreads();

        // ---- QK^T, 1-pass f16 ----
        floatx4 s[4];
#pragma unroll
        for (int j = 0; j < 4; ++j) {
            const int row = j * 16 + l15;
            const int base = row * 64;
            half8 k0 = *(const half8*)&sK[base + ((quad + row) & 7) * 8];
            half8 k1 = *(const half8*)&sK[base + ((quad + 4 + row) & 7) * 8];
            s[j] = (floatx4){0.f, 0.f, 0.f, 0.f};
            s[j] = MFMA16F(aq0, k0, s[j]);
            s[j] = MFMA16F(aq1, k1, s[j]);
        }

        // ---- V fragments (f16) ----
        half8 gv0[4], gv1[4];
#pragma unroll
        for (int j2 = 0; j2 < 4; ++j2) {
            const int row = j2 * 16 + l15;
            const int base = row * 64;
            gv0[j2] = *(const half8*)&sV[base + ((quad + row) & 7) * 8];
            gv1[j2] = *(const half8*)&sV[base + ((quad + 4 + row) & 7) * 8];
        }

        // ---- exp, S store, P pack (f16, scaled 2^60) ----
#pragma unroll
        for (int j = 0; j < 4; ++j) {
#pragma unroll
            for (int r = 0; r < 4; ++r) {
                const float val = __expf(2.f * s[j][r] - q2v[r] - k2v[j]);
                const int row = q0 + 16 * w + quad * 4 + r;
                S[Sz + (size_t)row * 1024 + col0 + j * 16 + l15] = val;
                P[(16 * w + quad * 4 + r) * 72 + j * 16 + l15] =
                    __builtin_bit_cast(ushort_t, (_Float16)(val * P_SCALE));
            }
        }

        // ---- P readback (A-layout, wave-local) + S@V, f16 ----
        half8 pf0 = *(const half8*)&P[(16 * w + l15) * 72 + quad * 8];
        half8 pf1 = *(const half8*)&P[(16 * w + l15) * 72 + 32 + quad * 8];
#pragma unroll
        for (int j2 = 0; j2 < 4; ++j2) {
            oacc[j2] = MFMA16F(pf0, gv0[j2], oacc[j2]);
            oacc[j2] = MFMA16F(pf1, gv1[j2], oacc[j2]);
        }
        __syncthreads();
    }

#pragma unroll
    for (int j2 = 0; j2 < 4; ++j2)
#pragma unroll
        for (int r = 0; r < 4; ++r) {
            const int row = q0 + 16 * w + quad * 4 + r;
            attn[(size_t)(b * 1024 + row) * 512 + h * 64 + j2 * 16 + l15] =
                f2b(oacc[j2][r] * P_ISCALE);
        }
}

extern "C" void kernel_launch(void* const* d_in, const int* in_sizes, int n_in,
                              void* d_out, int out_size, void* d_ws, size_t ws_size,
                              hipStream_t stream)
{
    const float* query = (const float*)d_in[0];
    const float* key   = (const float*)d_in[1];
    const float* value = (const float*)d_in[2];
    const float* Wq    = (const float*)d_in[3];
    const float* Wk    = (const float*)d_in[4];
    const float* Wv    = (const float*)d_in[5];
    const float* Wo    = (const float*)d_in[6];

    float* out  = (float*)d_out;
    float* Sout = out + (size_t)8192 * 512;

    const size_t NE = (size_t)8192 * 512;
    ushort_t* qh_f16  = (ushort_t*)d_ws;
    ushort_t* kh_f16  = qh_f16 + NE;
    ushort_t* vhT     = kh_f16 + NE;
    ushort_t* attn_bf = vhT + NE;
    ushort_t* WqT_hi  = attn_bf + NE;
    ushort_t* WqT_lo  = WqT_hi + 262144;
    ushort_t* WkT_hi  = WqT_lo + 262144;
    ushort_t* WkT_lo  = WkT_hi + 262144;
    ushort_t* WvT     = WkT_lo + 262144;
    ushort_t* WoT     = WvT + 262144;
    float*    q2      = (float*)(WoT + 262144);
    float*    k2      = q2 + 65536;

    wt_cvt<<<dim3(64, 4), 256, 0, stream>>>(Wq, Wk, Wv, Wo, WqT_hi, WqT_lo,
                                            WkT_hi, WkT_lo, WvT, WoT);

    gemm_lds<float, 3, 1><<<1024, 256, 0, stream>>>(
        query, WqT_hi, WqT_lo, nullptr, qh_f16, nullptr, q2);
    gemm_lds<float, 3, 1><<<1024, 256, 0, stream>>>(
        key, WkT_hi, WkT_lo, nullptr, kh_f16, nullptr, k2);
    gemm_lds<float, 1, 2><<<1024, 256, 0, stream>>>(
        value, WvT, nullptr, nullptr, vhT, nullptr, nullptr);

    flash_rbf<<<1024, 256, 0, stream>>>(qh_f16, kh_f16, vhT, q2, k2,
                                        Sout, attn_bf);

    gemm_lds<ushort_t, 1, 0><<<1024, 256, 0, stream>>>(
        attn_bf, WoT, nullptr, out, nullptr, nullptr, nullptr);
}

// Round 7
// 430.694 us; speedup vs baseline: 1.1234x; 1.0267x over previous
//
#include <hip/hip_runtime.h>

// (B,T,D,H,KD)=(8,1024,512,8,64), SIGMA=1.
// d_out: out [8*1024*512] f32, then attn_weights [64][1024][1024] f32.
// R11: full-fp16 pipeline.  R10's diagnostic: absmax (2.168e-19) is set by
// the OUT path (attn->bf16 + Wo bf16, rel 2^-8), not QK precision.  So:
// (a) attn stored f16 AT the 2^60 scale (range safe: P stores the same
//     scaled values in f16 and passed), Wo stored f16, out GEMM f16xf16
//     with x2^-60 in the epilogue -> out-path error ~8x lower;
// (b) projections go 1-pass f16 (was 3-pass bf16 hi/lo): MFMAs 12->4 per
//     K-step, no B-lo staging, 64-op split VALU -> 8 v_cvt_f16_f32.
//     q2/k2 still from the f16-ROUNDED qh/kh (exact ||q~-k~||^2 in flash);
// (c) v path f16 end-to-end (more accurate than R10's bf16xbf16).
// Flash unchanged from R10 (best structure: 4 waves, 25.2KB, 4 blocks/CU).

typedef float  floatx4 __attribute__((ext_vector_type(4)));
typedef _Float16 half8 __attribute__((ext_vector_type(8)));
typedef unsigned short ushort_t;

#define MFMA16F(a, b, c) __builtin_amdgcn_mfma_f32_16x16x32_f16((a), (b), (c), 0, 0, 0)

#define P_SCALE   0x1p60f
#define P_ISCALE  0x1p-60f

// Async global->LDS, 16B per lane.  LDS dest = wave-uniform base + lane*16.
__device__ inline void gl_lds16(const void* g, void* l) {
    __builtin_amdgcn_global_load_lds(
        (const __attribute__((address_space(1))) unsigned int*)g,
        (__attribute__((address_space(3))) unsigned int*)l, 16, 0, 0);
}

// ---------------------------------------------------------------------------
// Weight transpose via LDS tile (coalesced both sides): WT[n][k] = f16(W[k][n]).
// grid (64 tiles, 4 weights), 256 threads; tile = 64(k) x 64(n).
// ---------------------------------------------------------------------------
__global__ __launch_bounds__(256) void wt_cvt(
    const float* __restrict__ Wq, const float* __restrict__ Wk,
    const float* __restrict__ Wv, const float* __restrict__ Wo,
    ushort_t* __restrict__ qT, ushort_t* __restrict__ kT,
    ushort_t* __restrict__ vT, ushort_t* __restrict__ oT)
{
    __shared__ float sT[64][65];
    const int tid = threadIdx.x;
    const int c = tid & 63, rq = tid >> 6;
    const int bx = blockIdx.x;
    const int k0 = (bx >> 3) * 64, n0 = (bx & 7) * 64;

    const float* W; ushort_t* H;
    switch (blockIdx.y) {
        case 0:  W = Wq; H = qT; break;
        case 1:  W = Wk; H = kT; break;
        case 2:  W = Wv; H = vT; break;
        default: W = Wo; H = oT; break;
    }

#pragma unroll
    for (int i = 0; i < 16; ++i) {
        const int row = i * 4 + rq;                      // k within tile
        sT[row][c] = W[(size_t)(k0 + row) * 512 + n0 + c];
    }
    __syncthreads();
#pragma unroll
    for (int i = 0; i < 16; ++i) {
        const int nrow = i * 4 + rq;                     // n within tile
        ((_Float16*)H)[(size_t)(n0 + nrow) * 512 + k0 + c] = (_Float16)sT[c][nrow];
    }
}

// ---------------------------------------------------------------------------
// LDS-staged f16 MFMA GEMM, K=512, tile 64x64, BK=32, 256 threads (4 waves,
// wave w owns rows 16w..16w+15 x all 64 cols).  grid = 1024: mt=gid>>3,
// nt=gid&7 (gid%8 = n-panel -> per-XCD B locality).
// 2-phase prefetch: double-buffered LDS, stage(it+1) issued before
// compute(it), single barrier/iter.  B always f16.
// AF32 true: A fp32 staged raw, f16 cast after LDS read (8 v_cvt/iter).
// AF32 false: A f16 staged directly.  1 MFMA per ni per iter.
// OUTMODE 0: out f32 = acc * 2^-60 (A carries the 2^60 P scale).
// OUTMODE 1: f16 + fused row-norms from the ROUNDED value -> normOut[z][t]
// (64-col n-panel = one head; flash then sees exact ||q~-k~||^2).
// OUTMODE 2: vhT[z][d][T] f16.
// Chunk swizzle: LDS slot = (chunk + row) % nchunks -> conflict-free reads.
// ---------------------------------------------------------------------------
template <bool AF32, int OUTMODE>
__global__ __launch_bounds__(256) void gemm_f16(
    const void* __restrict__ A, const ushort_t* __restrict__ BT,
    float* __restrict__ outF, ushort_t* __restrict__ outH,
    float* __restrict__ normOut)
{
    __shared__ __align__(16) float    sAf[AF32 ? 2 * 64 * 32 : 4];   // fp32 A dbuf
    __shared__ __align__(16) ushort_t sAh[AF32 ? 8 : 2 * 64 * 32];   // f16 A dbuf
    __shared__ __align__(16) ushort_t sB [2 * 64 * 32];              // f16 B dbuf

    const int tid = threadIdx.x;
    const int w = tid >> 6, lane = tid & 63;
    const int l15 = lane & 15, quad = lane >> 4;
    const int gid = blockIdx.x;
    const int m0 = (gid >> 3) * 64, n0 = (gid & 7) * 64;

    auto STAGE = [&](int bi, int it) {
        const int k0 = it * 32;
        if constexpr (AF32) {
            // A tile 64x32 f32 = 8KB: rows of 8 chunks, swizzled.
#pragma unroll
            for (int t = 0; t < 2; ++t) {
                const int c = (w * 2 + t) * 64 + lane;
                const int row = c >> 3, slot = c & 7, kch = (slot - row) & 7;
                gl_lds16((const float*)A + (size_t)(m0 + row) * 512 + k0 + kch * 4,
                         (char*)sAf + (size_t)bi * 8192 + (size_t)(w * 2 + t) * 1024);
            }
        } else {
            // A tile 64x32 f16 = 4KB: rows of 4 chunks.
            const int c = w * 64 + lane;
            const int row = c >> 2, slot = c & 3, kch = (slot - row) & 3;
            gl_lds16((const ushort_t*)A + (size_t)(m0 + row) * 512 + k0 + kch * 8,
                     (char*)sAh + (size_t)bi * 4096 + (size_t)w * 1024);
        }
        {
            const int c = w * 64 + lane;
            const int row = c >> 2, slot = c & 3, kch = (slot - row) & 3;
            gl_lds16(BT + (size_t)(n0 + row) * 512 + k0 + kch * 8,
                     (char*)sB + (size_t)bi * 4096 + (size_t)w * 1024);
        }
    };

    floatx4 acc[4];
#pragma unroll
    for (int i = 0; i < 4; ++i) acc[i] = (floatx4){0.f, 0.f, 0.f, 0.f};

    STAGE(0, 0);
    __syncthreads();
    int cur = 0;

    for (int it = 0; it < 16; ++it) {
        if (it + 1 < 16) STAGE(cur ^ 1, it + 1);   // prefetch, drains at barrier

        const float*    Af = sAf + (size_t)cur * (AF32 ? 64 * 32 : 0);
        const ushort_t* Ah = sAh + (size_t)cur * (AF32 ? 0 : 64 * 32);
        const ushort_t* Bb = sB  + (size_t)cur * (64 * 32);

        // ---- fragments ----
        half8 ah;
        {
            const int row = 16 * w + l15;
            if constexpr (AF32) {
                float4 f0 = *(const float4*)&Af[row * 32 + ((quad * 2 + row) & 7) * 4];
                float4 f1 = *(const float4*)&Af[row * 32 + ((quad * 2 + 1 + row) & 7) * 4];
                ah[0] = (_Float16)f0.x; ah[1] = (_Float16)f0.y;
                ah[2] = (_Float16)f0.z; ah[3] = (_Float16)f0.w;
                ah[4] = (_Float16)f1.x; ah[5] = (_Float16)f1.y;
                ah[6] = (_Float16)f1.z; ah[7] = (_Float16)f1.w;
            } else {
                ah = *(const half8*)&Ah[row * 32 + ((quad + row) & 3) * 8];
            }
        }
        half8 bh[4];
#pragma unroll
        for (int ni = 0; ni < 4; ++ni) {
            const int row = ni * 16 + l15;
            bh[ni] = *(const half8*)&Bb[row * 32 + ((quad + row) & 3) * 8];
        }
        // ---- MFMAs ----
#pragma unroll
        for (int ni = 0; ni < 4; ++ni)
            acc[ni] = MFMA16F(ah, bh[ni], acc[ni]);
        __syncthreads();
        cur ^= 1;
    }

    // ---- epilogue ----
#pragma unroll
    for (int ni = 0; ni < 4; ++ni) {
        const int n = n0 + ni * 16 + l15;
#pragma unroll
        for (int r = 0; r < 4; ++r) {
            const int m = m0 + 16 * w + quad * 4 + r;
            const float v = acc[ni][r];
            if (OUTMODE == 0) {
                outF[(size_t)m * 512 + n] = v * P_ISCALE;
            } else if (OUTMODE == 1) {
                ((_Float16*)outH)[(size_t)m * 512 + n] = (_Float16)v;
            } else {
                const int b = m >> 10, t = m & 1023, hh = n >> 6, d = n & 63;
                ((_Float16*)outH)[((size_t)(b * 8 + hh) * 64 + d) * 1024 + t] =
                    (_Float16)v;
            }
        }
    }
    if (OUTMODE == 1) {
        // Fused per-head squared norms from the f16-ROUNDED values (must
        // match what flash reads for exact ||q~-k~||^2 expansion).
#pragma unroll
        for (int r = 0; r < 4; ++r) {
            float s2 = 0.f;
#pragma unroll
            for (int ni = 0; ni < 4; ++ni) {
                const float rv = (float)(_Float16)acc[ni][r];
                s2 = fmaf(rv, rv, s2);
            }
#pragma unroll
            for (int off = 1; off < 16; off <<= 1) s2 += __shfl_xor(s2, off);
            if (l15 == 0) {
                const int m = m0 + 16 * w + quad * 4 + r;
                normOut[(size_t)((m >> 10) * 8 + (gid & 7)) * 1024 + (m & 1023)] = s2;
            }
        }
    }
}

// ---------------------------------------------------------------------------
// Fused flash (R10 structure, fp16): block = (z, 64 q-rows), 4 waves;
// gid = qt*64+z so gid%8==h (XCD L2 locality for K/V).  Per 64-col tile:
// stage K/V^T f16 (2x8KB, swizzled) -> barrier -> QK 1-pass f16 MFMA ->
// exp -> S store + P strip (f16, x2^60) -> SV f16 MFMA -> barrier.
// 25.2KB LDS -> 4+ blocks/CU.  attn stored f16 AT the 2^60 scale (out GEMM
// applies 2^-60); range safe: P holds the same scaled values in f16.
// ---------------------------------------------------------------------------
__global__ __launch_bounds__(256) void flash_rbf(
    const ushort_t* __restrict__ qh, const ushort_t* __restrict__ kh,
    const ushort_t* __restrict__ vhT, const float* __restrict__ q2,
    const float* __restrict__ k2, float* __restrict__ S,
    ushort_t* __restrict__ attn)
{
    __shared__ __align__(16) ushort_t sK[64 * 64];
    __shared__ __align__(16) ushort_t sV[64 * 64];
    __shared__ __align__(16) ushort_t P [64 * 72];

    const int tid = threadIdx.x;
    const int w = tid >> 6, lane = tid & 63;
    const int l15 = lane & 15, quad = lane >> 4;
    const int gid = blockIdx.x;
    const int z = gid & 63, qt = gid >> 6;
    const int b = z >> 3, h = z & 7;
    const int q0 = qt * 64;

    // Q fragments (f16 registers, whole block).
    const size_t qrow = (size_t)(b * 1024 + q0 + 16 * w + l15) * 512 + h * 64 + quad * 8;
    half8 aq0 = *(const half8*)((const _Float16*)qh + qrow);
    half8 aq1 = *(const half8*)((const _Float16*)qh + qrow + 32);

    float q2v[4];
#pragma unroll
    for (int r = 0; r < 4; ++r)
        q2v[r] = q2[(size_t)z * 1024 + q0 + 16 * w + quad * 4 + r];

    floatx4 oacc[4];
#pragma unroll
    for (int i = 0; i < 4; ++i) oacc[i] = (floatx4){0.f, 0.f, 0.f, 0.f};

    const size_t Sz = (size_t)z << 20;

    for (int ct = 0; ct < 16; ++ct) {
        const int col0 = ct * 64;

        // ---- stage K + V^T f16 tiles (rows of 8 chunks, swizzled) ----
#pragma unroll
        for (int t = 0; t < 2; ++t) {
            const int c = (w * 2 + t) * 64 + lane;
            const int row = c >> 3, slot = c & 7, dch = (slot - row) & 7;
            const size_t ke = (size_t)(b * 1024 + col0 + row) * 512 + h * 64 + dch * 8;
            const size_t ve = ((size_t)z * 64 + row) * 1024 + col0 + dch * 8;
            gl_lds16(kh + ke,  (char*)sK + (size_t)(w * 2 + t) * 1024);
            gl_lds16(vhT + ve, (char*)sV + (size_t)(w * 2 + t) * 1024);
        }
        float k2v[4];
#pragma unroll
        for (int j = 0; j < 4; ++j)
            k2v[j] = k2[(size_t)z * 1024 + col0 + j * 16 + l15];
        __syncthreads();

        // ---- QK^T, 1-pass f16 ----
        floatx4 s[4];
#pragma unroll
        for (int j = 0; j < 4; ++j) {
            const int row = j * 16 + l15;
            const int base = row * 64;
            half8 k0 = *(const half8*)&sK[base + ((quad + row) & 7) * 8];
            half8 k1 = *(const half8*)&sK[base + ((quad + 4 + row) & 7) * 8];
            s[j] = (floatx4){0.f, 0.f, 0.f, 0.f};
            s[j] = MFMA16F(aq0, k0, s[j]);
            s[j] = MFMA16F(aq1, k1, s[j]);
        }

        // ---- V fragments (f16) ----
        half8 gv0[4], gv1[4];
#pragma unroll
        for (int j2 = 0; j2 < 4; ++j2) {
            const int row = j2 * 16 + l15;
            const int base = row * 64;
            gv0[j2] = *(const half8*)&sV[base + ((quad + row) & 7) * 8];
            gv1[j2] = *(const half8*)&sV[base + ((quad + 4 + row) & 7) * 8];
        }

        // ---- exp, S store, P pack (f16, scaled 2^60) ----
#pragma unroll
        for (int j = 0; j < 4; ++j) {
#pragma unroll
            for (int r = 0; r < 4; ++r) {
                const float val = __expf(2.f * s[j][r] - q2v[r] - k2v[j]);
                const int row = q0 + 16 * w + quad * 4 + r;
                S[Sz + (size_t)row * 1024 + col0 + j * 16 + l15] = val;
                P[(16 * w + quad * 4 + r) * 72 + j * 16 + l15] =
                    __builtin_bit_cast(ushort_t, (_Float16)(val * P_SCALE));
            }
        }

        // ---- P readback (A-layout, wave-local) + S@V, f16 ----
        half8 pf0 = *(const half8*)&P[(16 * w + l15) * 72 + quad * 8];
        half8 pf1 = *(const half8*)&P[(16 * w + l15) * 72 + 32 + quad * 8];
#pragma unroll
        for (int j2 = 0; j2 < 4; ++j2) {
            oacc[j2] = MFMA16F(pf0, gv0[j2], oacc[j2]);
            oacc[j2] = MFMA16F(pf1, gv1[j2], oacc[j2]);
        }
        __syncthreads();
    }

    // attn stored f16 at the 2^60 scale (out GEMM applies 2^-60).
#pragma unroll
    for (int j2 = 0; j2 < 4; ++j2)
#pragma unroll
        for (int r = 0; r < 4; ++r) {
            const int row = q0 + 16 * w + quad * 4 + r;
            ((_Float16*)attn)[(size_t)(b * 1024 + row) * 512 + h * 64 + j2 * 16 + l15] =
                (_Float16)oacc[j2][r];
        }
}

extern "C" void kernel_launch(void* const* d_in, const int* in_sizes, int n_in,
                              void* d_out, int out_size, void* d_ws, size_t ws_size,
                              hipStream_t stream)
{
    const float* query = (const float*)d_in[0];
    const float* key   = (const float*)d_in[1];
    const float* value = (const float*)d_in[2];
    const float* Wq    = (const float*)d_in[3];
    const float* Wk    = (const float*)d_in[4];
    const float* Wv    = (const float*)d_in[5];
    const float* Wo    = (const float*)d_in[6];

    float* out  = (float*)d_out;
    float* Sout = out + (size_t)8192 * 512;

    const size_t NE = (size_t)8192 * 512;
    ushort_t* qh_f16   = (ushort_t*)d_ws;
    ushort_t* kh_f16   = qh_f16 + NE;
    ushort_t* vhT      = kh_f16 + NE;
    ushort_t* attn_f16 = vhT + NE;
    ushort_t* WqT      = attn_f16 + NE;
    ushort_t* WkT      = WqT + 262144;
    ushort_t* WvT      = WkT + 262144;
    ushort_t* WoT      = WvT + 262144;
    float*    q2       = (float*)(WoT + 262144);
    float*    k2       = q2 + 65536;

    wt_cvt<<<dim3(64, 4), 256, 0, stream>>>(Wq, Wk, Wv, Wo, WqT, WkT, WvT, WoT);

    gemm_f16<true, 1><<<1024, 256, 0, stream>>>(
        query, WqT, nullptr, qh_f16, q2);
    gemm_f16<true, 1><<<1024, 256, 0, stream>>>(
        key, WkT, nullptr, kh_f16, k2);
    gemm_f16<true, 2><<<1024, 256, 0, stream>>>(
        value, WvT, nullptr, vhT, nullptr);

    flash_rbf<<<1024, 256, 0, stream>>>(qh_f16, kh_f16, vhT, q2, k2,
                                        Sout, attn_f16);

    gemm_f16<false, 0><<<1024, 256, 0, stream>>>(
        attn_f16, WoT, out, nullptr, nullptr);
}